// Round 1
// baseline (202.761 us; speedup 1.0000x reference)
//
#include <hip/hip_runtime.h>

#define NB 4
#define NP 32768
#define NK 16
#define ND 8
#define EPSV 1e-6f

// accum layout in d_ws: accum[0..7] = sum_d, accum[8..15] = sumsq_d

__global__ __launch_bounds__(256) void lse_stats(
    const float* __restrict__ coords,
    const int*   __restrict__ knn_idx,
    const float* __restrict__ knn_dist,
    const int*   __restrict__ mask,
    const float* __restrict__ conv_w,
    const float* __restrict__ conv_b,
    float*       __restrict__ accum)
{
    const int gid = blockIdx.x * 256 + threadIdx.x;   // one thread per (b,n)
    const int b = gid >> 15;                          // NP = 2^15
    const int n = gid & (NP - 1);

    // Folded weights: x_d = a·c + e·c_j + w9*dist + b_d   (uniform -> SGPRs)
    float a0[ND], a1[ND], a2[ND], e0[ND], e1[ND], e2[ND], w9[ND], cb[ND];
#pragma unroll
    for (int d = 0; d < ND; ++d) {
        const float* w = conv_w + d * 10;
        float w0 = w[0], w1 = w[1], w2 = w[2];
        float w3 = w[3], w4 = w[4], w5 = w[5];
        float w6 = w[6], w7 = w[7], w8 = w[8];
        a0[d] = w0 + w6; a1[d] = w1 + w7; a2[d] = w2 + w8;
        e0[d] = w3 - w6; e1[d] = w4 - w7; e2[d] = w5 - w8;
        w9[d] = w[9];    cb[d] = conv_b[d];
    }

    const float* cbase = coords + (size_t)b * NP * 3;
    const float cx = cbase[n * 3 + 0];
    const float cy = cbase[n * 3 + 1];
    const float cz = cbase[n * 3 + 2];
    const int   mk = mask[b * NP + n];

    const int4*   idx4 = (const int4*)(knn_idx + ((size_t)gid) * NK);
    const float4* dst4 = (const float4*)(knn_dist + ((size_t)gid) * NK);

    float cterm[ND];
#pragma unroll
    for (int d = 0; d < ND; ++d)
        cterm[d] = fmaf(a0[d], cx, fmaf(a1[d], cy, fmaf(a2[d], cz, cb[d])));

    float sum[ND], sq[ND];
#pragma unroll
    for (int d = 0; d < ND; ++d) { sum[d] = 0.f; sq[d] = 0.f; }

#pragma unroll
    for (int q = 0; q < 4; ++q) {
        int4   id = idx4[q];
        float4 dv = dst4[q];
        int   js[4] = {id.x, id.y, id.z, id.w};
        float dsv[4] = {dv.x, dv.y, dv.z, dv.w};
#pragma unroll
        for (int t = 0; t < 4; ++t) {
            int j = js[t] < 0 ? 0 : js[t];
            const float* nb = cbase + (size_t)j * 3;
            float nx = nb[0], ny = nb[1], nz = nb[2];
            float dist = (mk == 0) ? __builtin_inff() : dsv[t];
#pragma unroll
            for (int d = 0; d < ND; ++d) {
                float x = fmaf(e0[d], nx, fmaf(e1[d], ny,
                          fmaf(e2[d], nz, fmaf(w9[d], dist, cterm[d]))));
                sum[d] += x;
                sq[d]  = fmaf(x, x, sq[d]);
            }
        }
    }

    // wave(64) shuffle reduction on 16 accumulators
#pragma unroll
    for (int d = 0; d < ND; ++d) {
        float s = sum[d], s2 = sq[d];
#pragma unroll
        for (int off = 32; off > 0; off >>= 1) {
            s  += __shfl_down(s,  off);
            s2 += __shfl_down(s2, off);
        }
        sum[d] = s; sq[d] = s2;
    }

    __shared__ float lds[4][16];
    const int wave = threadIdx.x >> 6;
    const int lane = threadIdx.x & 63;
    if (lane == 0) {
#pragma unroll
        for (int d = 0; d < ND; ++d) {
            lds[wave][d]     = sum[d];
            lds[wave][8 + d] = sq[d];
        }
    }
    __syncthreads();
    if (threadIdx.x < 16) {
        float v = lds[0][threadIdx.x] + lds[1][threadIdx.x]
                + lds[2][threadIdx.x] + lds[3][threadIdx.x];
        atomicAdd(&accum[threadIdx.x], v);
    }
}

__global__ __launch_bounds__(256) void lse_main(
    const float* __restrict__ coords,
    const float* __restrict__ features,
    const int*   __restrict__ knn_idx,
    const float* __restrict__ knn_dist,
    const int*   __restrict__ mask,
    const float* __restrict__ conv_w,
    const float* __restrict__ conv_b,
    const float* __restrict__ bn_gamma,
    const float* __restrict__ bn_beta,
    const float* __restrict__ accum,
    float*       __restrict__ out)
{
    const int gid = blockIdx.x * 256 + threadIdx.x;   // one thread per (b,n,k)
    const int b     = gid >> 19;                      // NP*NK = 2^19
    const int local = gid & (NP * NK - 1);
    const int n     = local >> 4;                     // NK = 16

    // BN affine fold (uniform): y = x*scale + shift, then relu
    const float invM = 1.0f / (float)(NB * NP * NK);
    float scale[ND], shift[ND];
#pragma unroll
    for (int d = 0; d < ND; ++d) {
        float mean = accum[d] * invM;
        float var  = fmaf(-mean, mean, accum[8 + d] * invM);
        float g    = bn_gamma[d] * rsqrtf(var + EPSV);
        scale[d] = g;
        shift[d] = fmaf(-mean, g, bn_beta[d]);
    }

    float a0[ND], a1[ND], a2[ND], e0[ND], e1[ND], e2[ND], w9[ND], cb[ND];
#pragma unroll
    for (int d = 0; d < ND; ++d) {
        const float* w = conv_w + d * 10;
        float w0 = w[0], w1 = w[1], w2 = w[2];
        float w3 = w[3], w4 = w[4], w5 = w[5];
        float w6 = w[6], w7 = w[7], w8 = w[8];
        a0[d] = w0 + w6; a1[d] = w1 + w7; a2[d] = w2 + w8;
        e0[d] = w3 - w6; e1[d] = w4 - w7; e2[d] = w5 - w8;
        w9[d] = w[9];    cb[d] = conv_b[d];
    }

    const float* cbase = coords + (size_t)b * NP * 3;
    const float cx = cbase[n * 3 + 0];
    const float cy = cbase[n * 3 + 1];
    const float cz = cbase[n * 3 + 2];

    int j = knn_idx[gid]; j = j < 0 ? 0 : j;
    const float nx = cbase[j * 3 + 0];
    const float ny = cbase[j * 3 + 1];
    const float nz = cbase[j * 3 + 2];

    const int   mk   = mask[b * NP + n];
    const float dist = (mk == 0) ? __builtin_inff() : knn_dist[gid];

    const size_t obase = (size_t)b * (2 * ND) * NP * NK + (size_t)local;
    const size_t cstr  = (size_t)NP * NK;

#pragma unroll
    for (int d = 0; d < ND; ++d) {
        float x = fmaf(a0[d], cx, fmaf(a1[d], cy, fmaf(a2[d], cz,
                  fmaf(e0[d], nx, fmaf(e1[d], ny, fmaf(e2[d], nz,
                  fmaf(w9[d], dist, cb[d])))))));
        float y = fmaf(x, scale[d], shift[d]);
        out[obase + (size_t)d * cstr] = fmaxf(y, 0.f);
    }

    const float* fbase = features + (size_t)b * ND * NP;
#pragma unroll
    for (int d = 0; d < ND; ++d) {
        out[obase + (size_t)(ND + d) * cstr] = fbase[d * NP + n];
    }
}

extern "C" void kernel_launch(void* const* d_in, const int* in_sizes, int n_in,
                              void* d_out, int out_size, void* d_ws, size_t ws_size,
                              hipStream_t stream) {
    const float* coords   = (const float*)d_in[0];
    const float* features = (const float*)d_in[1];
    const int*   knn_idx  = (const int*)  d_in[2];
    const float* knn_dist = (const float*)d_in[3];
    const int*   mask     = (const int*)  d_in[4];
    const float* conv_w   = (const float*)d_in[5];
    const float* conv_b   = (const float*)d_in[6];
    const float* bn_gamma = (const float*)d_in[7];
    const float* bn_beta  = (const float*)d_in[8];
    float* out   = (float*)d_out;
    float* accum = (float*)d_ws;   // 16 floats

    hipMemsetAsync(accum, 0, 16 * sizeof(float), stream);

    // stats: one thread per (b,n) -> 131072 threads
    lse_stats<<<(NB * NP) / 256, 256, 0, stream>>>(
        coords, knn_idx, knn_dist, mask, conv_w, conv_b, accum);

    // main: one thread per (b,n,k) -> 2097152 threads
    lse_main<<<(NB * NP * NK) / 256, 256, 0, stream>>>(
        coords, features, knn_idx, knn_dist, mask, conv_w, conv_b,
        bn_gamma, bn_beta, accum, out);
}

// Round 3
// 196.270 us; speedup vs baseline: 1.0331x; 1.0331x over previous
//
#include <hip/hip_runtime.h>
#include <hip/hip_fp16.h>

#define NB 4
#define NP 32768
#define NK 16
#define ND 8
#define EPSV 1e-6f

// d_ws layout: [0..64)   : 16 float accumulators (sum[8], sumsq[8])
//              [256..)   : fp16 x-stage, (B,D,N,K) = 32 MB (if ws allows)

// ---------------- Pass 1: gather + conv, stage x, write feature planes, stats ----------
// one thread per (b, n, kq) with kq = k/4  ->  4*32768*4 = 524288 threads, 2048 blocks
__global__ __launch_bounds__(256) void lse_pass1(
    const float* __restrict__ coords,
    const float* __restrict__ features,
    const int*   __restrict__ knn_idx,
    const float* __restrict__ knn_dist,
    const int*   __restrict__ mask,
    const float* __restrict__ conv_w,
    const float* __restrict__ conv_b,
    float*       __restrict__ accum,
    __half*      __restrict__ xstage,   // nullptr -> stage fp32 into out instead
    float*       __restrict__ out)
{
    const int gid = blockIdx.x * 256 + threadIdx.x;
    const int b   = gid >> 17;                 // NP*4 = 2^17 threads per batch
    const int r   = gid & (NP * 4 - 1);
    const int n   = r >> 2;
    const int k0  = (r & 3) * 4;

    // Folded 1x1-conv weights: x_d = a.c + e.c_j + w9*dist + cb   (thread-uniform)
    float a0[ND], a1[ND], a2[ND], e0[ND], e1[ND], e2[ND], w9[ND], cb[ND];
#pragma unroll
    for (int d = 0; d < ND; ++d) {
        const float* w = conv_w + d * 10;
        float w0 = w[0], w1 = w[1], w2 = w[2];
        float w3 = w[3], w4 = w[4], w5 = w[5];
        float w6 = w[6], w7 = w[7], w8 = w[8];
        a0[d] = w0 + w6; a1[d] = w1 + w7; a2[d] = w2 + w8;
        e0[d] = w3 - w6; e1[d] = w4 - w7; e2[d] = w5 - w8;
        w9[d] = w[9];    cb[d] = conv_b[d];
    }

    const float* cbase = coords + (size_t)b * NP * 3;
    const float  cx = cbase[n * 3 + 0];
    const float  cy = cbase[n * 3 + 1];
    const float  cz = cbase[n * 3 + 2];

    const size_t p  = ((size_t)(b * NP + n)) * NK + k0;
    const int4   id = *(const int4*)(knn_idx + p);     // 16B coalesced
    float4       dv = *(const float4*)(knn_dist + p);  // 16B coalesced
    if (mask[b * NP + n] == 0) {
        dv.x = dv.y = dv.z = dv.w = __builtin_inff();
    }

    const int   js[4] = {id.x < 0 ? 0 : id.x, id.y < 0 ? 0 : id.y,
                         id.z < 0 ? 0 : id.z, id.w < 0 ? 0 : id.w};
    const float ds[4] = {dv.x, dv.y, dv.z, dv.w};

    float xv[4][ND];
    float sum[ND], sq[ND];
#pragma unroll
    for (int d = 0; d < ND; ++d) { sum[d] = 0.f; sq[d] = 0.f; }

#pragma unroll
    for (int t = 0; t < 4; ++t) {
        const float* nb = cbase + (size_t)js[t] * 3;   // L2-resident gather
        const float  nx = nb[0], ny = nb[1], nz = nb[2];
#pragma unroll
        for (int d = 0; d < ND; ++d) {
            float x = fmaf(a0[d], cx, fmaf(a1[d], cy, fmaf(a2[d], cz,
                      fmaf(e0[d], nx, fmaf(e1[d], ny, fmaf(e2[d], nz,
                      fmaf(w9[d], ds[t], cb[d])))))));
            xv[t][d] = x;
            sum[d] += x;
            sq[d]   = fmaf(x, x, sq[d]);
        }
    }

    // stage x: fp16 into ws (preferred) or fp32 into out
    if (xstage) {
#pragma unroll
        for (int d = 0; d < ND; ++d) {
            __half2* o2 = (__half2*)(xstage +
                ((((size_t)(b * ND + d)) * NP + n) << 4) + k0);   // 8B aligned
            o2[0] = __floats2half2_rn(xv[0][d], xv[1][d]);
            o2[1] = __floats2half2_rn(xv[2][d], xv[3][d]);
        }
    } else {
#pragma unroll
        for (int d = 0; d < ND; ++d) {
            *(float4*)(out + ((((size_t)(b * 2 * ND + d)) * NP + n) << 4) + k0) =
                make_float4(xv[0][d], xv[1][d], xv[2][d], xv[3][d]);
        }
    }

    // BN-independent feature broadcast planes (channels ND..2ND)
    const float* fb = features + (size_t)b * ND * NP;
#pragma unroll
    for (int d = 0; d < ND; ++d) {
        const float v = fb[d * NP + n];
        *(float4*)(out + ((((size_t)(b * 2 * ND + ND + d)) * NP + n) << 4) + k0) =
            make_float4(v, v, v, v);
    }

    // ---- stats reduction: wave shuffle -> LDS -> 16 atomics per block ----
#pragma unroll
    for (int d = 0; d < ND; ++d) {
        float s = sum[d], s2 = sq[d];
#pragma unroll
        for (int off = 32; off > 0; off >>= 1) {
            s  += __shfl_down(s,  off);
            s2 += __shfl_down(s2, off);
        }
        sum[d] = s; sq[d] = s2;
    }
    __shared__ float lds[4][16];
    const int wave = threadIdx.x >> 6, lane = threadIdx.x & 63;
    if (lane == 0) {
#pragma unroll
        for (int d = 0; d < ND; ++d) {
            lds[wave][d]     = sum[d];
            lds[wave][8 + d] = sq[d];
        }
    }
    __syncthreads();
    if (threadIdx.x < 16) {
        float v = lds[0][threadIdx.x] + lds[1][threadIdx.x]
                + lds[2][threadIdx.x] + lds[3][threadIdx.x];
        atomicAdd(&accum[threadIdx.x], v);
    }
}

// ---------------- Pass 2: normalize + relu, streaming ----------------------------------
// one thread per 8 x-elements -> 16777216/8 = 2097152 threads, 8192 blocks
__global__ __launch_bounds__(256) void lse_pass2(
    const float*  __restrict__ accum,
    const float*  __restrict__ bn_gamma,
    const float*  __restrict__ bn_beta,
    const __half* __restrict__ xstage,   // nullptr -> x staged fp32 in out
    float*        __restrict__ out)
{
    const int    gid = blockIdx.x * 256 + threadIdx.x;
    const size_t s0  = (size_t)gid * 8;              // flat (b,d,n,k) x-index
    const int    d   = (int)((s0 >> 19) & 7);        // plane = NP*NK = 2^19
    const int    b   = (int)(s0 >> 22);              // 8 planes per batch
    const size_t inp = s0 & ((1u << 19) - 1);
    const size_t o   = (((size_t)(b * 2 * ND + d)) << 19) | inp;

    const float invM = 1.0f / (float)(NB * NP * NK);
    const float mean = accum[d] * invM;
    const float var  = fmaf(-mean, mean, accum[8 + d] * invM);
    const float g    = bn_gamma[d] * rsqrtf(var + EPSV);
    const float sh   = fmaf(-mean, g, bn_beta[d]);

    float x[8];
    if (xstage) {
        const float4 raw = *(const float4*)(xstage + s0);   // 8 halfs, 16B
        const __half2* h = (const __half2*)&raw;
#pragma unroll
        for (int q = 0; q < 4; ++q) {
            float2 f = __half22float2(h[q]);
            x[2 * q]     = f.x;
            x[2 * q + 1] = f.y;
        }
    } else {
        const float4 v0 = *(const float4*)(out + o);
        const float4 v1 = *(const float4*)(out + o + 4);
        x[0] = v0.x; x[1] = v0.y; x[2] = v0.z; x[3] = v0.w;
        x[4] = v1.x; x[5] = v1.y; x[6] = v1.z; x[7] = v1.w;
    }

    float4 r0, r1;
    r0.x = fmaxf(fmaf(x[0], g, sh), 0.f);
    r0.y = fmaxf(fmaf(x[1], g, sh), 0.f);
    r0.z = fmaxf(fmaf(x[2], g, sh), 0.f);
    r0.w = fmaxf(fmaf(x[3], g, sh), 0.f);
    r1.x = fmaxf(fmaf(x[4], g, sh), 0.f);
    r1.y = fmaxf(fmaf(x[5], g, sh), 0.f);
    r1.z = fmaxf(fmaf(x[6], g, sh), 0.f);
    r1.w = fmaxf(fmaf(x[7], g, sh), 0.f);
    *(float4*)(out + o)     = r0;
    *(float4*)(out + o + 4) = r1;
}

extern "C" void kernel_launch(void* const* d_in, const int* in_sizes, int n_in,
                              void* d_out, int out_size, void* d_ws, size_t ws_size,
                              hipStream_t stream) {
    const float* coords   = (const float*)d_in[0];
    const float* features = (const float*)d_in[1];
    const int*   knn_idx  = (const int*)  d_in[2];
    const float* knn_dist = (const float*)d_in[3];
    const int*   mask     = (const int*)  d_in[4];
    const float* conv_w   = (const float*)d_in[5];
    const float* conv_b   = (const float*)d_in[6];
    const float* bn_gamma = (const float*)d_in[7];
    const float* bn_beta  = (const float*)d_in[8];
    float* out   = (float*)d_out;
    float* accum = (float*)d_ws;   // 16 floats

    hipMemsetAsync(d_ws, 0, 64, stream);

    __half* xstage = nullptr;
    const size_t need = 256 + (size_t)NB * ND * NP * NK * sizeof(__half);  // ~32 MB
    if (ws_size >= need) xstage = (__half*)((char*)d_ws + 256);

    // pass 1: 524288 threads
    lse_pass1<<<(NB * NP * 4) / 256, 256, 0, stream>>>(
        coords, features, knn_idx, knn_dist, mask, conv_w, conv_b,
        accum, xstage, out);

    // pass 2: 2097152 threads
    lse_pass2<<<(NB * ND * NP * NK / 8) / 256, 256, 0, stream>>>(
        accum, bn_gamma, bn_beta, xstage, out);
}